// Round 1
// baseline (488.577 us; speedup 1.0000x reference)
//
#include <hip/hip_runtime.h>
#include <math.h>

#define BATCH 8
#define NPTS  4096
#define TPB   256

// One thread = one query point. Inner loop over all NPTS candidates of the
// same batch; candidate loads are wave-uniform -> expect s_load scalar
// broadcasts, pure-VALU inner loop (3 sub + 3 fma/mul + 1 min per candidate).
__global__ __launch_bounds__(TPB) void chamfer_kernel(
    const float* __restrict__ input,
    const float* __restrict__ target,
    float* __restrict__ out)
{
    const int dir = blockIdx.z;               // 0: input->target, 1: target->input
    const int b   = blockIdx.y;

    const float* __restrict__ src = dir ? target : input;
    const float* __restrict__ dst = dir ? input  : target;
    const float* __restrict__ sp  = src + (size_t)b * NPTS * 3;
    const float* __restrict__ dp  = dst + (size_t)b * NPTS * 3;

    const int n = blockIdx.x * TPB + threadIdx.x;   // query point index (always < NPTS)
    const float px = sp[3 * n + 0];
    const float py = sp[3 * n + 1];
    const float pz = sp[3 * n + 2];

    float best = 3.4e38f;
    #pragma unroll 8
    for (int m = 0; m < NPTS; ++m) {
        const float dx = px - dp[3 * m + 0];
        const float dy = py - dp[3 * m + 1];
        const float dz = pz - dp[3 * m + 2];
        const float d  = fmaf(dx, dx, fmaf(dy, dy, dz * dz));
        best = fminf(best, d);
    }

    // Sum of per-point nearest distances: wave shuffle reduce, then LDS across
    // the 4 waves, then one atomicAdd per block.
    float s = best;
    #pragma unroll
    for (int off = 32; off > 0; off >>= 1)
        s += __shfl_down(s, off, 64);

    __shared__ float wsum[TPB / 64];
    const int wid = threadIdx.x >> 6;
    const int lid = threadIdx.x & 63;
    if (lid == 0) wsum[wid] = s;
    __syncthreads();

    if (threadIdx.x == 0) {
        float t = 0.0f;
        #pragma unroll
        for (int w = 0; w < TPB / 64; ++w) t += wsum[w];
        // mean over B*NPTS for this direction; both directions add into out.
        atomicAdd(out, t * (1.0f / (float)(BATCH * NPTS)));
    }
}

extern "C" void kernel_launch(void* const* d_in, const int* in_sizes, int n_in,
                              void* d_out, int out_size, void* d_ws, size_t ws_size,
                              hipStream_t stream) {
    const float* input  = (const float*)d_in[0];   // [B, N, 3] fp32
    const float* target = (const float*)d_in[1];   // [B, M, 3] fp32
    float* out = (float*)d_out;                    // scalar fp32

    // Harness poisons d_out with 0xAA before every timed call — zero it.
    hipMemsetAsync(out, 0, sizeof(float), stream);

    dim3 grid(NPTS / TPB, BATCH, 2);
    dim3 block(TPB);
    chamfer_kernel<<<grid, block, 0, stream>>>(input, target, out);
}

// Round 2
// 83.632 us; speedup vs baseline: 5.8420x; 5.8420x over previous
//
#include <hip/hip_runtime.h>
#include <math.h>

#define BATCH  8
#define NPTS   4096
#define TPB    256
#define QPT    4                 // queries per thread (independent min chains)
#define QCHUNK (TPB * QPT)       // 1024 queries per block
#define NQC    (NPTS / QCHUNK)   // 4 query chunks
#define NCC    16                // candidate chunks (parallelism multiplier)
#define CTILE  (NPTS / NCC)      // 256 candidates per chunk

// Partial-min kernel: block = (query chunk qc, candidate chunk cc, batch, dir).
// Candidates staged in LDS as (-2cx, -2cy, -2cz, ||c||^2) so each pair costs
// 3 FMA + 1 min. Per-query ||x||^2 is added after the loop (monotone with min),
// clamped >= 0, then combined across candidate chunks via uint atomicMin.
__global__ __launch_bounds__(TPB) void chamfer_min_kernel(
    const float* __restrict__ input,
    const float* __restrict__ target,
    unsigned int* __restrict__ best)   // [2][BATCH][NPTS] float bits
{
    const int dir = blockIdx.z;
    const int b   = blockIdx.y;
    const int qc  = blockIdx.x & (NQC - 1);
    const int cc  = blockIdx.x >> 2;          // NQC == 4

    const float* __restrict__ qp = (dir ? target : input) + (size_t)b * NPTS * 3;
    const float* __restrict__ cp = (dir ? input  : target) + (size_t)b * NPTS * 3;

    __shared__ float4 cand[CTILE];
    {
        const int c = cc * CTILE + threadIdx.x;   // CTILE == TPB: 1 per thread
        const float cx = cp[3 * c + 0];
        const float cy = cp[3 * c + 1];
        const float cz = cp[3 * c + 2];
        cand[threadIdx.x] = make_float4(-2.0f * cx, -2.0f * cy, -2.0f * cz,
                                        fmaf(cx, cx, fmaf(cy, cy, cz * cz)));
    }

    // Q=4 contiguous queries per thread: 12 contiguous floats, coalesced.
    const int q0 = qc * QCHUNK + (int)threadIdx.x * QPT;
    float px[QPT], py[QPT], pz[QPT], pmin[QPT];
    #pragma unroll
    for (int k = 0; k < QPT; ++k) {
        px[k] = qp[3 * (q0 + k) + 0];
        py[k] = qp[3 * (q0 + k) + 1];
        pz[k] = qp[3 * (q0 + k) + 2];
        pmin[k] = 3.4e38f;
    }
    __syncthreads();

    #pragma unroll 4
    for (int m = 0; m < CTILE; ++m) {
        const float4 c = cand[m];                 // LDS broadcast read
        #pragma unroll
        for (int k = 0; k < QPT; ++k) {
            const float t = fmaf(px[k], c.x,
                            fmaf(py[k], c.y,
                            fmaf(pz[k], c.z, c.w)));   // ||c||^2 - 2 x.c
            pmin[k] = fminf(pmin[k], t);
        }
    }

    unsigned int* bq = best + ((size_t)(dir * BATCH + b)) * NPTS + q0;
    #pragma unroll
    for (int k = 0; k < QPT; ++k) {
        const float x2 = fmaf(px[k], px[k], fmaf(py[k], py[k], pz[k] * pz[k]));
        const float v  = fmaxf(pmin[k] + x2, 0.0f);    // matches ref's clamp
        atomicMin(&bq[k], __float_as_uint(v));         // nonneg: uint order == float order
    }
}

// Sum 2*BATCH*NPTS = 65536 partial minima -> mean(dir0) + mean(dir1).
__global__ __launch_bounds__(TPB) void chamfer_reduce_kernel(
    const unsigned int* __restrict__ best, float* __restrict__ out)
{
    const int i = (blockIdx.x * TPB + (int)threadIdx.x) * 4;
    const uint4 u = *(const uint4*)(best + i);
    float s = __uint_as_float(u.x) + __uint_as_float(u.y) +
              __uint_as_float(u.z) + __uint_as_float(u.w);
    #pragma unroll
    for (int off = 32; off > 0; off >>= 1)
        s += __shfl_down(s, off, 64);

    __shared__ float wsum[TPB / 64];
    if ((threadIdx.x & 63) == 0) wsum[threadIdx.x >> 6] = s;
    __syncthreads();
    if (threadIdx.x == 0) {
        const float t = wsum[0] + wsum[1] + wsum[2] + wsum[3];
        atomicAdd(out, t * (1.0f / (float)(BATCH * NPTS)));
    }
}

extern "C" void kernel_launch(void* const* d_in, const int* in_sizes, int n_in,
                              void* d_out, int out_size, void* d_ws, size_t ws_size,
                              hipStream_t stream) {
    const float* input  = (const float*)d_in[0];   // [B, N, 3] fp32
    const float* target = (const float*)d_in[1];   // [B, M, 3] fp32
    float* out = (float*)d_out;
    unsigned int* best = (unsigned int*)d_ws;      // 2*BATCH*NPTS uints = 256 KB

    // Init: best = 0x7F7F7F7F (= 3.39e38f as float, acts as +inf); out = 0.
    hipMemsetAsync(best, 0x7F, (size_t)2 * BATCH * NPTS * sizeof(unsigned int), stream);
    hipMemsetAsync(out, 0, sizeof(float), stream);

    dim3 grid1(NQC * NCC, BATCH, 2);               // 64 x 8 x 2 = 1024 blocks
    chamfer_min_kernel<<<grid1, dim3(TPB), 0, stream>>>(input, target, best);

    dim3 grid2((2 * BATCH * NPTS) / (TPB * 4));    // 64 blocks
    chamfer_reduce_kernel<<<grid2, dim3(TPB), 0, stream>>>(best, out);
}